// Round 10
// baseline (39.602 us; speedup 1.0000x reference)
//
#include <hip/hip_runtime.h>

// y = convT3d(x, weight.sum(oc), stride=2, pad=2, k=5) + sum(bias); out = 6^3 stride-6 max.
// MFMA formulation (verified R6-R9, absmax 0.25): y[2m+t] = sum_{ic,abc} x[ic,m+1-abc]*w[ic,t+2abc]
//   D[16 w-cells x 8 parities] += A[cells x 32ic] * B[32ic x parities], 27 (a,b,c) chunks.
// R10: NO global xT. conv stages A per dpad-plane directly from fp32 x: lane=w reads 8 ic
//   (coalesced stride-CHSTR dwords), packs bf16 (RNE), ds_write_b128 into [r][wpad][ic] with
//   16B-slot XOR swizzle slot^=(col&3) applied on BOTH write and read (k-order preserved;
//   whalf +16 cols keeps col&3 -> +512 read offset still valid). B-frags from global Btab (R9).

typedef short v8s __attribute__((ext_vector_type(8)));
typedef float v4f __attribute__((ext_vector_type(4)));
typedef unsigned short ushort_t;

#define CHSTR 16384              // x ic-stride (16*32*32)
#define NSTRIDE (32*CHSTR)
#define Y_N 108000
#define Y_TOT (16*Y_N)
#define XSTR 24

#define WSF_BYTE_OFF 27648u      // Btab = 27*64*8*2 bytes
#define NEED_FUSED (27648u + 4097u*4u)

static __device__ __forceinline__ ushort_t f2bf(float f) {
  unsigned u = __builtin_bit_cast(unsigned, f);
  unsigned r = (u + 0x7FFFu + ((u >> 16) & 1u)) >> 16;
  return (ushort_t)r;
}
static __device__ __forceinline__ unsigned pk2(float a, float b) {
  return (unsigned)f2bf(a) | ((unsigned)f2bf(b) << 16);
}

// ---------------- prep: B fragment table + bias sum --------------------
__global__ __launch_bounds__(256) void prep_bw(const float* __restrict__ w,
                                               const float* __restrict__ bias,
                                               ushort_t* __restrict__ Btab,
                                               float* __restrict__ wsf) {
  int abc = blockIdx.x;               // a*9 + b*3 + c
  int a = abc / 9, b = (abc / 3) % 3, c = abc % 3;
  int t = threadIdx.x;
  int half = t & 3;                   // j-pair 2*half, 2*half+1
  int l = t >> 2;                     // lane 0..63
  int tt = l & 15, g = l >> 4;
  float v0 = 0.f, v1 = 0.f;
  if (tt < 8) {
    int td = tt & 1, th = (tt >> 1) & 1, tw = tt >> 2;
    int kd = td + 2 * a, kh = th + 2 * b, kw = tw + 2 * c;
    if (kd < 5 && kh < 5 && kw < 5) {
      int off = kd * 25 + kh * 5 + kw;
      const float* wp0 = w + (size_t)(8 * g + 2 * half) * 64 * 125 + off;
      const float* wp1 = wp0 + 64 * 125;
      float s0 = 0.f, s1 = 0.f;
#pragma unroll
      for (int oc = 0; oc < 64; ++oc) { s0 += wp0[oc * 125]; s1 += wp1[oc * 125]; }
      v0 = s0; v1 = s1;
    }
  }
  ((unsigned*)Btab)[(abc * 64 + l) * 4 + half] = (unsigned)f2bf(v0) | ((unsigned)f2bf(v1) << 16);
  if (abc == 0 && t == 0) {
    float bs = 0.f;
    for (int o = 0; o < 64; ++o) bs += bias[o];
    wsf[4096] = bs;
  }
}

// ---------------- fused transpose + MFMA conv + 6^3 pool ----------------
// 800 blocks = (n, OD, OH); 576 threads = 9 waves (mdl, mhl).
// LDS plane buffer: [5 r][34 col][32 ic] ushorts, 16B slots XOR-swizzled by (col&3).
__global__ __launch_bounds__(576, 7) void conv_fused(const float* __restrict__ x,
                                                     const ushort_t* __restrict__ Btab,
                                                     const float* __restrict__ wsf,
                                                     float* __restrict__ out) {
  __shared__ __align__(16) ushort_t As0[5440];
  __shared__ __align__(16) ushort_t As1[5440];
  __shared__ float ytile[6 * 6 * 64];
  __shared__ float red[64];

  int blk = blockIdx.x;
  int OH = blk % 10, OD = (blk / 10) % 5, n = blk / 50;
  int t = threadIdx.x;
  int wv = t >> 6, l = t & 63;
  int mdl = wv / 3, mhl = wv % 3;
  int tt = l & 15, g = l >> 4;

  // ---- staging lane constants (unit = 16 ic x 32 w x 1 r; 10 units/plane)
  int sw = l & 31, sich = l >> 5;     // w, 8-ic half
  int wcol = sw + 1;                  // wpad col 1..32
  int r_u = wv >> 1, icg_u = wv & 1;  // wave's unit: (r, 16-ic group); wave 8 also (4,1)
  bool hz_u = (3 * OH + r_u) == 0;    // h == -1 row (OH=0, r=0)
  const float* xu = x + (size_t)(n * 32 + icg_u * 16 + sich * 8) * CHSTR
                      + (3 * OH + r_u - 1) * 32 + sw;
  int waddr_u = ((r_u * 34 + wcol) << 5) + (((icg_u * 2 + sich) ^ (wcol & 3)) << 3);
  const float* xu9 = x + (size_t)(n * 32 + 16 + sich * 8) * CHSTR + (3 * OH + 3) * 32 + sw;
  int waddr_9 = ((4 * 34 + wcol) << 5) + (((2 + sich) ^ (wcol & 3)) << 3);

  // ---- compute lane constants: per-c A-read offsets (swizzled)
  int oc0 = ((2 + tt) << 5) + ((g ^ ((tt + 2) & 3)) << 3);
  int oc1 = ((1 + tt) << 5) + ((g ^ ((tt + 1) & 3)) << 3);
  int oc2 = ((tt) << 5)     + ((g ^ (tt & 3)) << 3);

  // ---- prologue: stage plane 0 (dpad = 3*OD; all-zero iff OD==0)
  {
    float f[8];
#pragma unroll
    for (int j = 0; j < 8; ++j) f[j] = 0.f;
    if (OD != 0 && !hz_u) {
      const float* s = xu + (size_t)(3 * OD - 1) * 1024;
#pragma unroll
      for (int j = 0; j < 8; ++j) f[j] = s[(size_t)j * CHSTR];
    }
    uint4 pk;
    pk.x = pk2(f[0], f[1]); pk.y = pk2(f[2], f[3]);
    pk.z = pk2(f[4], f[5]); pk.w = pk2(f[6], f[7]);
    *(uint4*)&As0[waddr_u] = pk;
    if (wv == 8) {
      float f9[8];
#pragma unroll
      for (int j = 0; j < 8; ++j) f9[j] = 0.f;
      if (OD != 0) {
        const float* s = xu9 + (size_t)(3 * OD - 1) * 1024;
#pragma unroll
        for (int j = 0; j < 8; ++j) f9[j] = s[(size_t)j * CHSTR];
      }
      uint4 p9;
      p9.x = pk2(f9[0], f9[1]); p9.y = pk2(f9[2], f9[3]);
      p9.z = pk2(f9[4], f9[5]); p9.w = pk2(f9[6], f9[7]);
      *(uint4*)&As0[waddr_9] = p9;
    }
    if (t < 160) {                    // zero cols 0 & 33 (persist; units never touch them)
      int seg = t >> 4;
      int rr = seg >> 1, col = (seg & 1) ? 33 : 0;
      *(unsigned*)&As0[((rr * 34 + col) << 5) + ((t & 15) << 1)] = 0u;
    }
  }
  __syncthreads();

  v4f acc0 = {0.f, 0.f, 0.f, 0.f};
  v4f acc1 = {0.f, 0.f, 0.f, 0.f};

  for (int p = 0; p < 5; ++p) {
    // ---- T14: prefetch plane p+1 loads into regs (in-loop planes never d-zero)
    float pf[8];
#pragma unroll
    for (int j = 0; j < 8; ++j) pf[j] = 0.f;
    if (p < 4 && !hz_u) {
      const float* s = xu + (size_t)(3 * OD + p) * 1024;
#pragma unroll
      for (int j = 0; j < 8; ++j) pf[j] = s[(size_t)j * CHSTR];
    }

    // ---- compute phase p (wave active if a = mdl+2-p in [0,2])
    int a = mdl + 2 - p;
    if (0 <= a && a <= 2) {
      const ushort_t* Ab = (p & 1) ? As1 : As0;
      const ushort_t* Bg = Btab + ((size_t)(a * 9) * 64 + l) * 8;
#pragma unroll
      for (int b = 0; b < 3; ++b) {
        int rb = (mhl + 2 - b) * 1088;
#pragma unroll
        for (int c = 0; c < 3; ++c) {
          int offc = (c == 0) ? oc0 : (c == 1) ? oc1 : oc2;
          v8s bv = *(const v8s*)(Bg + (b * 3 + c) * 512);
          const ushort_t* ap = Ab + rb + offc;
          v8s a0 = *(const v8s*)ap;
          v8s a1 = *(const v8s*)(ap + 512);   // whalf: +16 cols, col&3 invariant
          acc0 = __builtin_amdgcn_mfma_f32_16x16x32_bf16(a0, bv, acc0, 0, 0, 0);
          acc1 = __builtin_amdgcn_mfma_f32_16x16x32_bf16(a1, bv, acc1, 0, 0, 0);
        }
      }
    }

    // ---- pack + write next plane into other buffer, one barrier
    if (p < 4) {
      ushort_t* dst = (p & 1) ? As0 : As1;
      uint4 pk;
      pk.x = pk2(pf[0], pf[1]); pk.y = pk2(pf[2], pf[3]);
      pk.z = pk2(pf[4], pf[5]); pk.w = pk2(pf[6], pf[7]);
      *(uint4*)&dst[waddr_u] = pk;
      if (wv == 8) {                   // tail unit (r=4,icg=1): direct stage, never zero
        float f9[8];
        const float* s = xu9 + (size_t)(3 * OD + p) * 1024;
#pragma unroll
        for (int j = 0; j < 8; ++j) f9[j] = s[(size_t)j * CHSTR];
        uint4 p9;
        p9.x = pk2(f9[0], f9[1]); p9.y = pk2(f9[2], f9[3]);
        p9.z = pk2(f9[4], f9[5]); p9.w = pk2(f9[6], f9[7]);
        *(uint4*)&dst[waddr_9] = p9;
      }
      if (p == 0 && t < 160) {         // zero cols of second buffer, once
        int seg = t >> 4;
        int rr = seg >> 1, col = (seg & 1) ? 33 : 0;
        *(unsigned*)&dst[((rr * 34 + col) << 5) + ((t & 15) << 1)] = 0u;
      }
      __syncthreads();
    }
  }

  // ---- D scatter to ytile (layout verified R6)
  __syncthreads();
  if (tt < 8) {
    int td = tt & 1, th = (tt >> 1) & 1, tw = tt >> 2;
    int odl = 2 * mdl + td, ohl = 2 * mhl + th;
#pragma unroll
    for (int i = 0; i < 4; ++i) {
      int mwD0 = 4 * g + i;
      ytile[(odl * 6 + ohl) * 64 + 2 * mwD0 + tw] = acc0[i];
      ytile[(odl * 6 + ohl) * 64 + 2 * (16 + mwD0) + tw] = acc1[i];
    }
  }
  __syncthreads();

  if (t < 60) {
    int odl = t / 10, OW = t % 10;
    float m = -3.4e38f;
    for (int oh = 0; oh < 6; ++oh)
#pragma unroll
      for (int j = 0; j < 6; ++j)
        m = fmaxf(m, ytile[(odl * 6 + oh) * 64 + 6 * OW + j]);
    red[t] = m;
  }
  __syncthreads();
  if (t < 10) {
    float m = red[t];
#pragma unroll
    for (int odl = 1; odl < 6; ++odl) m = fmaxf(m, red[odl * 10 + t]);
    out[((n * 5 + OD) * 10 + OH) * 10 + t] = m + wsf[4096];
  }
}

// ================= fallback: R5 verified fp32 path (tiny ws) ===========
__global__ __launch_bounds__(128) void prep2(const float* __restrict__ w,
                                             const float* __restrict__ bias,
                                             float* __restrict__ ws, int woff) {
  int i = blockIdx.x, t = threadIdx.x;
  if (t < 125) {
    const float* wp = w + (size_t)i * 64 * 125 + t;
    float v = 0.f;
#pragma unroll
    for (int o = 0; o < 64; ++o) v += wp[o * 125];
    ws[woff + i * 128 + t] = v;
  }
  if (i == 0 && t == 126) {
    float b = 0.f;
    for (int o = 0; o < 64; ++o) b += bias[o];
    ws[woff + 4096] = b;
  }
}

__global__ __launch_bounds__(256, 4) void conv_stage1(const float* __restrict__ x,
                                                      const float* __restrict__ ws,
                                                      float* part, int woff) {
  __shared__ __align__(16) float xs[170 * XSTR];
  int blk = blockIdx.x;
  int s0 = blk % 320;
  int wq = s0 & 1, hq = (s0 >> 1) & 1, dc = (s0 >> 2) % 5, n = s0 / 20;
  int t = threadIdx.x;
  int mw = t % 15, lmh = t / 15;
  int id_base = 3 * dc - 1, ih_base = 15 * hq - 1;
  int iwb = wq ? 12 : -4;
  int cb = mw + (wq ? 2 : 3);
  const float* xn = x + (size_t)n * NSTRIDE;
  const float* wsw = ws + woff;
  float acc[3][2][2][2] = {{{{0.f}}}};
  for (int phs = 0; phs < 16; ++phs) {
    for (int s = t; s < 1700; s += 256) {
      int c2 = s % 10, row = s / 10;
      int bh = row % 17, q = row / 17;
      int ad = q % 5, lic = q / 5;
      int id = id_base + ad, ih = ih_base + bh, iw = iwb + 2 * c2;
      float2 v = make_float2(0.f, 0.f);
      if ((id | ih | iw) >= 0)
        v = *(const float2*)&xn[(size_t)(phs * 2 + lic) * CHSTR + (id * 32 + ih) * 32 + iw];
      *(float2*)&xs[row * XSTR + 2 * c2] = v;
    }
    __syncthreads();
    if (t < 225) {
#pragma unroll
      for (int lic = 0; lic < 2; ++lic) {
        const float* wc = wsw + (size_t)(phs * 2 + lic) * 128;
        const float* xc = &xs[(lic * 85 + lmh) * XSTR + cb];
        float xv[5][3][3];
#pragma unroll
        for (int a = 0; a < 5; ++a)
#pragma unroll
          for (int b = 0; b < 3; ++b) {
            const float* xr = xc + (a * 17 + b) * XSTR;
            xv[a][b][0] = xr[0]; xv[a][b][1] = xr[1]; xv[a][b][2] = xr[2];
          }
#pragma unroll
        for (int kd = 0; kd < 5; ++kd) {
          constexpr int DT[5] = {0, 1, 0, 1, 0};
          constexpr int AOFF[5] = {2, 2, 1, 1, 0};
          const int dt = DT[kd], aoff = AOFF[kd];
          float wvv[25];
#pragma unroll
          for (int j = 0; j < 25; ++j) wvv[j] = wc[kd * 25 + j];
#pragma unroll
          for (int kh = 0; kh < 5; ++kh) {
            constexpr int HT[5] = {0, 1, 0, 1, 0};
            constexpr int BOFF[5] = {2, 2, 1, 1, 0};
            const int ht = HT[kh], boff = BOFF[kh];
#pragma unroll
            for (int m = 0; m < 3; ++m) {
              const float x0 = xv[m + aoff][boff][0];
              const float x1 = xv[m + aoff][boff][1];
              const float x2 = xv[m + aoff][boff][2];
              acc[m][dt][ht][0] += x0 * wvv[kh * 5 + 4];
              acc[m][dt][ht][0] += x1 * wvv[kh * 5 + 2];
              acc[m][dt][ht][0] += x2 * wvv[kh * 5 + 0];
              acc[m][dt][ht][1] += x1 * wvv[kh * 5 + 3];
              acc[m][dt][ht][1] += x2 * wvv[kh * 5 + 1];
            }
          }
        }
      }
    }
    __syncthreads();
  }
  if (t < 225) {
    float* pb = part + (size_t)n * Y_N;
#pragma unroll
    for (int m = 0; m < 3; ++m)
#pragma unroll
      for (int dt = 0; dt < 2; ++dt)
#pragma unroll
        for (int ht = 0; ht < 2; ++ht) {
          int od_g = 6 * dc + 2 * m + dt;
          int oh_g = 30 * hq + 2 * lmh + ht;
          int ow_g = 30 * wq + 2 * mw;
          *(float2*)&pb[(od_g * 60 + oh_g) * 60 + ow_g] =
              make_float2(acc[m][dt][ht][0], acc[m][dt][ht][1]);
        }
  }
}

__global__ __launch_bounds__(256) void pool_stage2(const float* __restrict__ part,
                                                   const float* __restrict__ ws,
                                                   float* __restrict__ out, int woff) {
  __shared__ __align__(16) float buf[2160];
  __shared__ float red[240];
  int blk = blockIdx.x;
  int hc = blk % 10, dc = (blk / 10) % 5, n = blk / 50;
  int t = threadIdx.x;
  const float* pb = part + (size_t)n * Y_N;
  for (int s = t; s < 540; s += 256) {
    int row = s / 15, c4 = s % 15;
    int od = row / 6, oh = row % 6;
    size_t idx = (size_t)((6 * dc + od) * 60 + (6 * hc + oh)) * 60 + 4 * c4;
    *(float4*)&buf[row * 60 + 4 * c4] = *(const float4*)&pb[idx];
  }
  __syncthreads();
  if (t < 240) {
    int wc = t / 24, sub = t % 24;
    float m = -3.4e38f;
#pragma unroll
    for (int k = 0; k < 9; ++k) {
      int e = sub + 24 * k;
      int od = e / 36, r = e % 36;
      int oh = r / 6, ow0 = r % 6;
      m = fmaxf(m, buf[(od * 6 + oh) * 60 + 6 * wc + ow0]);
    }
    red[t] = m;
  }
  __syncthreads();
  if (t < 10) {
    float mm = -3.4e38f;
#pragma unroll
    for (int s2 = 0; s2 < 24; ++s2) mm = fmaxf(mm, red[t * 24 + s2]);
    out[((n * 5 + dc) * 10 + hc) * 10 + t] = mm + ws[woff + 4096];
  }
}

// ---------------- launch ----------------------------------------------
extern "C" void kernel_launch(void* const* d_in, const int* in_sizes, int n_in,
                              void* d_out, int out_size, void* d_ws, size_t ws_size,
                              hipStream_t stream) {
  const float* x    = (const float*)d_in[0];
  const float* w    = (const float*)d_in[1];
  const float* bias = (const float*)d_in[2];
  float* outp = (float*)d_out;

  if (ws_size >= (size_t)NEED_FUSED) {
    ushort_t* Bt = (ushort_t*)d_ws;
    float* wsf   = (float*)((char*)d_ws + WSF_BYTE_OFF);
    prep_bw<<<27, 256, 0, stream>>>(w, bias, Bt, wsf);
    conv_fused<<<800, 576, 0, stream>>>(x, Bt, wsf, outp);
    return;
  }

  // fp32 fallback (needs ~6.9 MB ws)
  float* ws = (float*)d_ws;
  const size_t need1 = ((size_t)1 * Y_TOT + 4097) * 4;
  if (ws_size >= need1) {
    int woff = Y_TOT;
    prep2<<<32, 128, 0, stream>>>(w, bias, ws, woff);
    conv_stage1<<<320, 256, 0, stream>>>(x, ws, ws, woff);
    pool_stage2<<<800, 256, 0, stream>>>(ws, ws, outp, woff);
  }
}

// Round 11
// 36.046 us; speedup vs baseline: 1.0987x; 1.0987x over previous
//
#include <hip/hip_runtime.h>

// y = convT3d(x, weight.sum(oc), stride=2, pad=2, k=5) + sum(bias); out = 6^3 stride-6 max.
// MFMA formulation (verified R6-R10, absmax 0.25): y[2m+t] = sum_{ic,abc} x[ic,m+1-abc]*w[ic,t+2abc]
//   D[16 w-cells x 8 parities] += A[cells x 32ic] * B[32ic x parities], 27 (a,b,c) chunks.
// xT: bf16 [n][dpad 18][hpad 34][wpad 34][ic 32], halos zeroed (dpad 0..16, hpad 0..31 written).
//   xT is the key cache structure: 21 MB bf16 -> L2-resident; conv A-reads are L2-served (R10
//   lesson: direct fp32 staging = 80 MB HBM re-read, -3.5 us regression).
// R11: conv block = 3od x 6oh (grid 400); wave owns TWO adjacent mh rows -> A-frag at row r
//   feeds (mh,b) and (mh+1,b+1) with the same read: 24 ds_read_b128 / 36 MFMA per wave-phase
//   (vs 18/18) = -33% LDS reads per MFMA. Plane slab is CONTIGUOUS in xT -> staging is a
//   linear 17.4 KB uint4 memcpy. ytile overlays dead A-buffers; B-frags from global Btab (R9).

typedef short v8s __attribute__((ext_vector_type(8)));
typedef float v4f __attribute__((ext_vector_type(4)));
typedef unsigned short ushort_t;

#define CHSTR 16384
#define NSTRIDE (32*CHSTR)
#define Y_N 108000
#define Y_TOT (16*Y_N)
#define XSTR 24

#define XT_US 10653696u          // 16*18*34*34*32 ushorts
#define XTN   665856u            // per-n: 18*34*34*32
#define PLANE_US 36992u          // 34*34*32
#define ROW_US 1088u             // 34*32
#define BT_BYTE_OFF 21307392u    // XT_US*2
#define WSF_BYTE_OFF 21335040u   // +27*64*8*2
#define NEED_MFMA (21335040u + 4097u*4u)

static __device__ __forceinline__ ushort_t f2bf(float f) {
  unsigned u = __builtin_bit_cast(unsigned, f);
  unsigned r = (u + 0x7FFFu + ((u >> 16) & 1u)) >> 16;
  return (ushort_t)r;
}

// ---------------- transpose x -> xT bf16  (+ folded prep for blk>=1088) --
// Verbatim from R9 (verified absmax 0.25).
__global__ __launch_bounds__(256) void transpose_x(const float* __restrict__ x,
                                                   const float* __restrict__ w,
                                                   const float* __restrict__ bias,
                                                   ushort_t* __restrict__ xT,
                                                   ushort_t* __restrict__ Btab,
                                                   float* __restrict__ wsf) {
  int blk = blockIdx.x;
  int t = threadIdx.x;

  if (blk >= 1088) {            // ---- prep path: B table from raw w
    int abc = blk - 1088;       // a*9 + b*3 + c
    int a = abc / 9, b = (abc / 3) % 3, c = abc % 3;
    int half = t & 3;
    int l = t >> 2;
    int tt = l & 15, g = l >> 4;
    float v0 = 0.f, v1 = 0.f;
    if (tt < 8) {
      int td = tt & 1, th = (tt >> 1) & 1, tw = tt >> 2;
      int kd = td + 2 * a, kh = th + 2 * b, kw = tw + 2 * c;
      if (kd < 5 && kh < 5 && kw < 5) {
        int off = kd * 25 + kh * 5 + kw;
        const float* wp0 = w + (size_t)(8 * g + 2 * half) * 64 * 125 + off;
        const float* wp1 = wp0 + 64 * 125;
        float s0 = 0.f, s1 = 0.f;
#pragma unroll
        for (int oc = 0; oc < 64; ++oc) { s0 += wp0[oc * 125]; s1 += wp1[oc * 125]; }
        v0 = s0; v1 = s1;
      }
    }
    ((unsigned*)Btab)[(abc * 64 + l) * 4 + half] = (unsigned)f2bf(v0) | ((unsigned)f2bf(v1) << 16);
    if (abc == 0 && t == 0) {
      float bsum = 0.f;
      for (int o = 0; o < 64; ++o) bsum += bias[o];
      wsf[4096] = bsum;
    }
    return;
  }

  int hq = blk & 3;
  int dpad = (blk >> 2) % 17;
  int n = blk / 68;
  int h0 = 8 * hq;
  ushort_t* plane = xT + (size_t)(n * 18 + dpad) * PLANE_US;
  int d = dpad - 1;

  if (d < 0) {                         // dpad==0 -> zero slice
    for (int r = 0; r < 8; ++r) {
      char* row = (char*)(plane + (size_t)(h0 + r) * ROW_US);
      for (int s = t; s < 136; s += 256)
        *(uint4*)(row + s * 16) = make_uint4(0, 0, 0, 0);
    }
    return;
  }

  __shared__ float lb[2][32 * 33];
  const float* xb = x + ((size_t)n * 32 * 16 + d) * 1024;
  int ic = t >> 3, wq = t & 7;

  {
    int h = h0 - 1;
    if (h >= 0) {
      float4 v = *(const float4*)&xb[(size_t)ic * 16384 + h * 32 + wq * 4];
      float* L = lb[0] + ic * 33 + wq * 4;
      L[0] = v.x; L[1] = v.y; L[2] = v.z; L[3] = v.w;
    }
  }
  int pp = 0;
  for (int i = 0; i < 8; ++i) {
    __syncthreads();
    if (i + 1 < 8) {
      int h = h0 + i;
      if (h <= 31) {
        float4 v = *(const float4*)&xb[(size_t)ic * 16384 + h * 32 + wq * 4];
        float* L = lb[pp ^ 1] + ic * 33 + wq * 4;
        L[0] = v.x; L[1] = v.y; L[2] = v.z; L[3] = v.w;
      }
    }
    int h = h0 + i - 1;
    ushort_t* row = plane + (size_t)(h0 + i) * ROW_US;
    bool hv = (h >= 0 && h <= 31);
    for (int s = t; s < 136; s += 256) {
      int wslot = s >> 2, q4 = s & 3;
      ushort_t o[8];
#pragma unroll
      for (int j = 0; j < 8; ++j) o[j] = 0;
      if (wslot >= 1 && wslot <= 32 && hv) {
        int w2 = wslot - 1;
        const float* L = lb[pp];
#pragma unroll
        for (int j = 0; j < 8; ++j) o[j] = f2bf(L[(8 * q4 + j) * 33 + w2]);
      }
      uint4 pk;
      pk.x = (unsigned)o[0] | ((unsigned)o[1] << 16);
      pk.y = (unsigned)o[2] | ((unsigned)o[3] << 16);
      pk.z = (unsigned)o[4] | ((unsigned)o[5] << 16);
      pk.w = (unsigned)o[6] | ((unsigned)o[7] << 16);
      *(uint4*)(row + wslot * 32 + q4 * 8) = pk;
    }
    pp ^= 1;
  }
}

// ---------------- fused MFMA conv + 6^3 pool (3od x 6oh blocks) ---------
// 400 blocks = (n, OD, OH2); 576 threads = 9 waves (mdl, mh-pair).
__global__ __launch_bounds__(576, 7) void conv_mfma6(const ushort_t* __restrict__ xT,
                                                     const ushort_t* __restrict__ Btab,
                                                     const float* __restrict__ wsf,
                                                     float* __restrict__ out) {
  __shared__ __align__(16) char smem[35328];
  ushort_t* As0 = (ushort_t*)smem;                 // 17408 B (8r x 34c x 32ic)
  ushort_t* As1 = (ushort_t*)(smem + 17408);       // 17408 B
  float* ytile  = (float*)smem;                    // 18432 B, overlays As0+start of As1 (dead)
  float* red    = (float*)(smem + 34816);          // 480 B

  int blk = blockIdx.x;
  int OH2 = blk % 5, OD = (blk / 5) % 5, n = blk / 25;
  int t = threadIdx.x;
  int wv = t >> 6, l = t & 63;
  int mdl = wv / 3, mhp = wv % 3;
  int tt = l & 15, g = l >> 4;

  const ushort_t* xn = xT + (size_t)n * XTN;
  // phase-p slab: contiguous 8704 ushorts at (dpad=3OD+p, rows 6OH2..6OH2+7)
  const ushort_t* slab0 = xn + ((size_t)(3 * OD) * 34 + 6 * OH2) * ROW_US;

  // ---- prologue: stage plane 0 (linear copy; dpad=0 slab is stored zeros)
  {
    uint4 v0 = *(const uint4*)(slab0 + (size_t)t * 8);
    uint4 v1;
    if (t < 512) v1 = *(const uint4*)(slab0 + (size_t)(t + 576) * 8);
    *(uint4*)&As0[t * 8] = v0;
    if (t < 512) *(uint4*)&As0[(t + 576) * 8] = v1;
  }
  __syncthreads();

  v4f acc[2][2];
#pragma unroll
  for (int m2 = 0; m2 < 2; ++m2)
#pragma unroll
    for (int wh = 0; wh < 2; ++wh) acc[m2][wh] = (v4f){0.f, 0.f, 0.f, 0.f};

  int lane_base = (2 * mhp) * ROW_US + tt * 32 + g * 8;   // row 2mhp, col tt, octet g

  for (int p = 0; p < 5; ++p) {
    // ---- T14: issue next plane's loads early
    uint4 v0, v1;
    if (p < 4) {
      const ushort_t* slab = slab0 + (size_t)(p + 1) * PLANE_US;
      v0 = *(const uint4*)(slab + (size_t)t * 8);
      if (t < 512) v1 = *(const uint4*)(slab + (size_t)(t + 576) * 8);
    }

    // ---- compute phase p (wave active if a = mdl+2-p in [0,2])
    int a = mdl + 2 - p;
    if (0 <= a && a <= 2) {
      const ushort_t* Ab = (p & 1) ? As1 : As0;
      const ushort_t* Bg = Btab + ((size_t)(a * 9) * 64 + l) * 8;
#pragma unroll
      for (int c = 0; c < 3; ++c) {
        v8s bv0 = *(const v8s*)(Bg + (0 * 3 + c) * 512);
        v8s bv1 = *(const v8s*)(Bg + (1 * 3 + c) * 512);
        v8s bv2 = *(const v8s*)(Bg + (2 * 3 + c) * 512);
#pragma unroll
        for (int wh = 0; wh < 2; ++wh) {
          const ushort_t* ap = Ab + lane_base + (2 - c + 16 * wh) * 32;
          v8s a0 = *(const v8s*)(ap);
          v8s a1 = *(const v8s*)(ap + 1 * ROW_US);
          v8s a2 = *(const v8s*)(ap + 2 * ROW_US);
          v8s a3 = *(const v8s*)(ap + 3 * ROW_US);
          // row j feeds (m2=0, b=2-j) and (m2=1, b=3-j)
          acc[0][wh] = __builtin_amdgcn_mfma_f32_16x16x32_bf16(a0, bv2, acc[0][wh], 0, 0, 0);
          acc[0][wh] = __builtin_amdgcn_mfma_f32_16x16x32_bf16(a1, bv1, acc[0][wh], 0, 0, 0);
          acc[0][wh] = __builtin_amdgcn_mfma_f32_16x16x32_bf16(a2, bv0, acc[0][wh], 0, 0, 0);
          acc[1][wh] = __builtin_amdgcn_mfma_f32_16x16x32_bf16(a1, bv2, acc[1][wh], 0, 0, 0);
          acc[1][wh] = __builtin_amdgcn_mfma_f32_16x16x32_bf16(a2, bv1, acc[1][wh], 0, 0, 0);
          acc[1][wh] = __builtin_amdgcn_mfma_f32_16x16x32_bf16(a3, bv0, acc[1][wh], 0, 0, 0);
        }
      }
    }

    // ---- write next plane into other buffer, one barrier
    if (p < 4) {
      ushort_t* dst = (p & 1) ? As0 : As1;
      *(uint4*)&dst[t * 8] = v0;
      if (t < 512) *(uint4*)&dst[(t + 576) * 8] = v1;
      __syncthreads();
    }
  }

  // ---- D scatter to ytile (C/D layout verified R6): rows=w-cells, cols=parities
  __syncthreads();
  if (tt < 8) {
    int td = tt & 1, th = (tt >> 1) & 1, tw = tt >> 2;
    int odl = 2 * mdl + td;
#pragma unroll
    for (int m2 = 0; m2 < 2; ++m2) {
      int ohl = 2 * (2 * mhp + m2) + th;
      float* yrow = &ytile[(odl * 12 + ohl) * 64];
#pragma unroll
      for (int wh = 0; wh < 2; ++wh)
#pragma unroll
        for (int i = 0; i < 4; ++i)
          yrow[2 * (16 * wh + 4 * g + i) + tw] = acc[m2][wh][i];
    }
  }
  __syncthreads();

  // ---- 6^3 pool: 120 threads = (odl 6, p_oh 2, OW 10)
  if (t < 120) {
    int OW = t % 10, p_oh = (t / 10) & 1, odl = t / 20;
    float m = -3.4e38f;
    for (int oh = 0; oh < 6; ++oh)
#pragma unroll
      for (int j = 0; j < 6; ++j)
        m = fmaxf(m, ytile[(odl * 12 + 6 * p_oh + oh) * 64 + 6 * OW + j]);
    red[t] = m;
  }
  __syncthreads();
  if (t < 20) {
    int OW = t % 10, p_oh = t / 10;
    float m = red[p_oh * 10 + OW];
#pragma unroll
    for (int odl = 1; odl < 6; ++odl) m = fmaxf(m, red[odl * 20 + p_oh * 10 + OW]);
    out[((n * 5 + OD) * 10 + (2 * OH2 + p_oh)) * 10 + OW] = m + wsf[4096];
  }
}

// ================= fallback: R5 verified fp32 path (tiny ws) ===========
__global__ __launch_bounds__(128) void prep2(const float* __restrict__ w,
                                             const float* __restrict__ bias,
                                             float* __restrict__ ws, int woff) {
  int i = blockIdx.x, t = threadIdx.x;
  if (t < 125) {
    const float* wp = w + (size_t)i * 64 * 125 + t;
    float v = 0.f;
#pragma unroll
    for (int o = 0; o < 64; ++o) v += wp[o * 125];
    ws[woff + i * 128 + t] = v;
  }
  if (i == 0 && t == 126) {
    float b = 0.f;
    for (int o = 0; o < 64; ++o) b += bias[o];
    ws[woff + 4096] = b;
  }
}

__global__ __launch_bounds__(256, 4) void conv_stage1(const float* __restrict__ x,
                                                      const float* __restrict__ ws,
                                                      float* part, int woff) {
  __shared__ __align__(16) float xs[170 * XSTR];
  int blk = blockIdx.x;
  int s0 = blk % 320;
  int wq = s0 & 1, hq = (s0 >> 1) & 1, dc = (s0 >> 2) % 5, n = s0 / 20;
  int t = threadIdx.x;
  int mw = t % 15, lmh = t / 15;
  int id_base = 3 * dc - 1, ih_base = 15 * hq - 1;
  int iwb = wq ? 12 : -4;
  int cb = mw + (wq ? 2 : 3);
  const float* xn = x + (size_t)n * NSTRIDE;
  const float* wsw = ws + woff;
  float acc[3][2][2][2] = {{{{0.f}}}};
  for (int phs = 0; phs < 16; ++phs) {
    for (int s = t; s < 1700; s += 256) {
      int c2 = s % 10, row = s / 10;
      int bh = row % 17, q = row / 17;
      int ad = q % 5, lic = q / 5;
      int id = id_base + ad, ih = ih_base + bh, iw = iwb + 2 * c2;
      float2 v = make_float2(0.f, 0.f);
      if ((id | ih | iw) >= 0)
        v = *(const float2*)&xn[(size_t)(phs * 2 + lic) * CHSTR + (id * 32 + ih) * 32 + iw];
      *(float2*)&xs[row * XSTR + 2 * c2] = v;
    }
    __syncthreads();
    if (t < 225) {
#pragma unroll
      for (int lic = 0; lic < 2; ++lic) {
        const float* wc = wsw + (size_t)(phs * 2 + lic) * 128;
        const float* xc = &xs[(lic * 85 + lmh) * XSTR + cb];
        float xv[5][3][3];
#pragma unroll
        for (int a = 0; a < 5; ++a)
#pragma unroll
          for (int b = 0; b < 3; ++b) {
            const float* xr = xc + (a * 17 + b) * XSTR;
            xv[a][b][0] = xr[0]; xv[a][b][1] = xr[1]; xv[a][b][2] = xr[2];
          }
#pragma unroll
        for (int kd = 0; kd < 5; ++kd) {
          constexpr int DT[5] = {0, 1, 0, 1, 0};
          constexpr int AOFF[5] = {2, 2, 1, 1, 0};
          const int dt = DT[kd], aoff = AOFF[kd];
          float wvv[25];
#pragma unroll
          for (int j = 0; j < 25; ++j) wvv[j] = wc[kd * 25 + j];
#pragma unroll
          for (int kh = 0; kh < 5; ++kh) {
            constexpr int HT[5] = {0, 1, 0, 1, 0};
            constexpr int BOFF[5] = {2, 2, 1, 1, 0};
            const int ht = HT[kh], boff = BOFF[kh];
#pragma unroll
            for (int m = 0; m < 3; ++m) {
              const float x0 = xv[m + aoff][boff][0];
              const float x1 = xv[m + aoff][boff][1];
              const float x2 = xv[m + aoff][boff][2];
              acc[m][dt][ht][0] += x0 * wvv[kh * 5 + 4];
              acc[m][dt][ht][0] += x1 * wvv[kh * 5 + 2];
              acc[m][dt][ht][0] += x2 * wvv[kh * 5 + 0];
              acc[m][dt][ht][1] += x1 * wvv[kh * 5 + 3];
              acc[m][dt][ht][1] += x2 * wvv[kh * 5 + 1];
            }
          }
        }
      }
    }
    __syncthreads();
  }
  if (t < 225) {
    float* pb = part + (size_t)n * Y_N;
#pragma unroll
    for (int m = 0; m < 3; ++m)
#pragma unroll
      for (int dt = 0; dt < 2; ++dt)
#pragma unroll
        for (int ht = 0; ht < 2; ++ht) {
          int od_g = 6 * dc + 2 * m + dt;
          int oh_g = 30 * hq + 2 * lmh + ht;
          int ow_g = 30 * wq + 2 * mw;
          *(float2*)&pb[(od_g * 60 + oh_g) * 60 + ow_g] =
              make_float2(acc[m][dt][ht][0], acc[m][dt][ht][1]);
        }
  }
}

__global__ __launch_bounds__(256) void pool_stage2(const float* __restrict__ part,
                                                   const float* __restrict__ ws,
                                                   float* __restrict__ out, int woff) {
  __shared__ __align__(16) float buf[2160];
  __shared__ float red[240];
  int blk = blockIdx.x;
  int hc = blk % 10, dc = (blk / 10) % 5, n = blk / 50;
  int t = threadIdx.x;
  const float* pb = part + (size_t)n * Y_N;
  for (int s = t; s < 540; s += 256) {
    int row = s / 15, c4 = s % 15;
    int od = row / 6, oh = row % 6;
    size_t idx = (size_t)((6 * dc + od) * 60 + (6 * hc + oh)) * 60 + 4 * c4;
    *(float4*)&buf[row * 60 + 4 * c4] = *(const float4*)&pb[idx];
  }
  __syncthreads();
  if (t < 240) {
    int wc = t / 24, sub = t % 24;
    float m = -3.4e38f;
#pragma unroll
    for (int k = 0; k < 9; ++k) {
      int e = sub + 24 * k;
      int od = e / 36, r = e % 36;
      int oh = r / 6, ow0 = r % 6;
      m = fmaxf(m, buf[(od * 6 + oh) * 60 + 6 * wc + ow0]);
    }
    red[t] = m;
  }
  __syncthreads();
  if (t < 10) {
    float mm = -3.4e38f;
#pragma unroll
    for (int s2 = 0; s2 < 24; ++s2) mm = fmaxf(mm, red[t * 24 + s2]);
    out[((n * 5 + dc) * 10 + hc) * 10 + t] = mm + ws[woff + 4096];
  }
}

// ---------------- launch ----------------------------------------------
extern "C" void kernel_launch(void* const* d_in, const int* in_sizes, int n_in,
                              void* d_out, int out_size, void* d_ws, size_t ws_size,
                              hipStream_t stream) {
  const float* x    = (const float*)d_in[0];
  const float* w    = (const float*)d_in[1];
  const float* bias = (const float*)d_in[2];
  float* outp = (float*)d_out;

  if (ws_size >= (size_t)NEED_MFMA) {
    ushort_t* xT = (ushort_t*)d_ws;
    ushort_t* Bt = (ushort_t*)((char*)d_ws + BT_BYTE_OFF);
    float* wsf   = (float*)((char*)d_ws + WSF_BYTE_OFF);
    transpose_x<<<1088 + 27, 256, 0, stream>>>(x, w, bias, xT, Bt, wsf);
    conv_mfma6<<<400, 576, 0, stream>>>(xT, Bt, wsf, outp);
    return;
  }

  // fp32 fallback (needs ~6.9 MB ws)
  float* ws = (float*)d_ws;
  const size_t need1 = ((size_t)1 * Y_TOT + 4097) * 4;
  if (ws_size >= need1) {
    int woff = Y_TOT;
    prep2<<<32, 128, 0, stream>>>(w, bias, ws, woff);
    conv_stage1<<<320, 256, 0, stream>>>(x, ws, ws, woff);
    pool_stage2<<<800, 256, 0, stream>>>(ws, ws, outp, woff);
  }
}